// Round 10
// baseline (174.123 us; speedup 1.0000x reference)
//
#include <hip/hip_runtime.h>
#include <cstdint>
#include <cstddef>

typedef _Float16 hf2   __attribute__((ext_vector_type(2)));
typedef _Float16 f16x8 __attribute__((ext_vector_type(8)));
typedef float    f32x4 __attribute__((ext_vector_type(4)));
typedef unsigned int u32x4 __attribute__((ext_vector_type(4)));

__device__ __forceinline__ f16x8 b2h8(u32x4 q) { union { u32x4 q; f16x8 h; } c; c.q = q; return c.h; }
__device__ __forceinline__ hf2 pkrtz(float lo, float hi) {
    auto v = __builtin_amdgcn_cvt_pkrtz(lo, hi);
    union { decltype(v) a; hf2 b; } c; c.a = v; return c.b;
}
__device__ __forceinline__ float lreluf(float x) { return fmaxf(x, 0.01f * x); }
// elementwise lrelu(a+b) on 8 packed f16
__device__ __forceinline__ f16x8 lrelu8(u32x4 a, u32x4 b) {
    f16x8 s = b2h8(a) + b2h8(b);
    f16x8 m = s * (_Float16)0.01f;
    return __builtin_elementwise_max(s, m);
}

// Pinned 16B global load: asm volatile so the scheduler can NEITHER sink it
// to its use (r7/r9 failure: VGPR squeezed to 52, loads serialized at full
// latency) NOR drop the batch issue order.
#define GLOAD(dst, ptr, off) \
    asm volatile("global_load_dwordx4 %0, %1, off offset:" #off \
                 : "=v"(dst) : "v"(ptr) : "memory")

// ---------------------------------------------------------------------------
// node projection + (extra blocks) weight packing + index-format detect.
// P[r][c] = (bias) + sum_k x[r][k] * W1[koff+k][c], stored f16.
__global__ __launch_bounds__(256) void node_proj2(
    const float* __restrict__ xd, const float* __restrict__ xi,
    const float* __restrict__ W1, const float* __restrict__ b1,
    _Float16* __restrict__ Pd, _Float16* __restrict__ Pi,
    int nd, int ni, int nblk_d, int nblk_i,
    const float* __restrict__ W2, const float* __restrict__ W3,
    _Float16* __restrict__ W2f, _Float16* __restrict__ W3f,
    const unsigned* __restrict__ ew, long long nwords, int* __restrict__ flag)
{
    const int t = threadIdx.x;
    const int nproj = nblk_d + nblk_i;

    if ((int)blockIdx.x >= nproj) {
        if ((int)blockIdx.x == nproj) {
            // W2 as MFMA B-fragments: frag(nt,kt), lane l, elem i ->
            //   B[k=kt*32+8*(l>>4)+i][col=nt*16+(l&15)]
            for (int idx = t; idx < 4096; idx += 256) {
                int i  = idx & 7;
                int l  = (idx >> 3) & 63;
                int kt = (idx >> 9) & 3;
                int nt = (idx >> 11) & 1;
                int k = kt * 32 + 8 * (l >> 4) + i;
                int j = nt * 16 + (l & 15);
                W2f[idx] = (_Float16)W2[k * 32 + j];
            }
            // W3^T as MFMA A-fragment: lane l, elem i -> W3[k=8*(l>>4)+i][row=l&15]
            for (int idx = t; idx < 512; idx += 256) {
                int i = idx & 7, l = idx >> 3;
                W3f[idx] = (_Float16)W3[(8 * (l >> 4) + i) * 16 + (l & 15)];
            }
        } else if (t < 64) {
            const long long pairs = nwords / 2;
            const long long step  = pairs / 64;
            unsigned v = 0;
            for (int s = 0; s < 4; ++s) {
                long long p = (long long)t * step + (long long)s * (step / 4 + 1);
                if (p < pairs) v |= ew[2 * p + 1];
            }
            unsigned long long ball = __ballot(v != 0);
            if (t == 0) *flag = (ball == 0ULL) ? 1 : 0;
        }
        return;
    }

    __shared__ float xs[1600];
    const int c  = t & 127;
    const int ty = t >> 7;
    const bool dis = (int)blockIdx.x >= nblk_d;
    const int b = dis ? (blockIdx.x - nblk_d) : blockIdx.x;
    const int n = dis ? ni : nd;
    const float* x = dis ? xi : xd;
    const float* W = dis ? (W1 + 100 * 128) : W1;
    _Float16* P = dis ? Pi : Pd;
    const float bv = dis ? b1[c] : 0.f;
    const int r0 = b * 16;

    const long long gbase = (long long)r0 * 100;
    const long long lim   = (long long)n * 100;
    for (int idx = t; idx < 1600; idx += 256) {
        long long g = gbase + idx;
        xs[idx] = (g < lim) ? x[g] : 0.f;
    }
    __syncthreads();

    float acc[8];
#pragma unroll
    for (int i = 0; i < 8; ++i) acc[i] = bv;

    const float4* xs4 = (const float4*)xs;
#pragma unroll 5
    for (int kk = 0; kk < 25; ++kk) {
        float w0 = W[(4 * kk + 0) * 128 + c];
        float w1 = W[(4 * kk + 1) * 128 + c];
        float w2 = W[(4 * kk + 2) * 128 + c];
        float w3 = W[(4 * kk + 3) * 128 + c];
#pragma unroll
        for (int i = 0; i < 8; ++i) {
            float4 xv = xs4[(ty * 8 + i) * 25 + kk];
            acc[i] = fmaf(xv.x, w0, acc[i]);
            acc[i] = fmaf(xv.y, w1, acc[i]);
            acc[i] = fmaf(xv.z, w2, acc[i]);
            acc[i] = fmaf(xv.w, w3, acc[i]);
        }
    }
#pragma unroll
    for (int i = 0; i < 8; ++i) {
        int r = r0 + ty * 8 + i;
        if (r < n) P[(size_t)r * 128 + c] = (_Float16)acc[i];
    }
}

// ---------------------------------------------------------------------------
// Edge MLP: 512 threads = 8 waves, ONE 16-edge tile per wave.
// Lane l's edge = base + (l&15); chunk = (l>>4)*16 -> the wave's 8 pinned
// asm gathers touch 16 rows x 4 chunks = 16 full 64B lines. One vmcnt(0)
// drain per wave; latency hidden by TLP (16 waves/CU x 8 loads in flight).
// Weights staged once per block via LDS. Zero barriers after the first.
__global__ __launch_bounds__(512, 4) void edge_mlp(
    const void* __restrict__ eidx_raw,
    const _Float16* __restrict__ Pd, const _Float16* __restrict__ Pi,
    const _Float16* __restrict__ W2f, const float* __restrict__ b2,
    const _Float16* __restrict__ W3f, const float* __restrict__ b3,
    const float* __restrict__ W4, const float* __restrict__ b4,
    const int* __restrict__ flag64,
    float* __restrict__ out, int E)
{
    // [0,512): W2 B-frags  [512,576): W3^T A-frag  [576,1216): 8 H2 slabs [16][40] f16
    __shared__ __align__(16) u32x4 Ws[1216];

    const int t  = threadIdx.x;
    const int l  = t & 63;
    const int w  = t >> 6;
    const int er = l & 15;
    const int cg = l >> 4;
    const int base = blockIdx.x * 128 + w * 16;

    // ---- stage weights to LDS (one pass, one barrier) ----
    Ws[t] = ((const u32x4*)W2f)[t];
    if (t < 64) Ws[512 + t] = ((const u32x4*)W3f)[t];
    __syncthreads();

    // ---- per-edge indices (4 lanes share an edge; same cache line) ----
    const int e_c = min(base + er, E - 1);
    int i0, i1;
    if (*flag64) {
        const long long* p = (const long long*)eidx_raw;
        i0 = (int)p[e_c];
        i1 = (int)p[(size_t)E + e_c];
    } else {
        const int* p = (const int*)eidx_raw;
        i0 = p[e_c];
        i1 = p[(size_t)E + e_c];
    }

    // ---- per-lane weight fragments from LDS ----
    f16x8 bf0[4], bf1[4];
#pragma unroll
    for (int kt = 0; kt < 4; ++kt) {
        bf0[kt] = b2h8(Ws[kt * 64 + l]);
        bf1[kt] = b2h8(Ws[256 + kt * 64 + l]);
    }
    const f16x8 w3f = b2h8(Ws[512 + l]);
    _Float16* Hw = (_Float16*)&Ws[576 + w * 80];

    const float  b2v0 = b2[er], b2v1 = b2[16 + er];
    const float4 b3q  = ((const float4*)b3)[cg];
    const float4 w4q  = ((const float4*)W4)[cg];
    const float  b4v  = b4[0];

    // ---- pinned gather: 8 asm loads, single drain ----
    const char* pD = (const char*)(Pd + (size_t)i0 * 128) + cg * 16;
    const char* pI = (const char*)(Pi + (size_t)i1 * 128) + cg * 16;
    u32x4 a0, a1, a2, a3, v0, v1, v2, v3;
    GLOAD(a0, pD, 0);
    GLOAD(a1, pD, 64);
    GLOAD(a2, pD, 128);
    GLOAD(a3, pD, 192);
    GLOAD(v0, pI, 0);
    GLOAD(v1, pI, 64);
    GLOAD(v2, pI, 128);
    GLOAD(v3, pI, 192);
    asm volatile("s_waitcnt vmcnt(0)" ::: "memory");
    __builtin_amdgcn_sched_barrier(0);   // rule #18: keep consumers below the wait

    // ---- layer 2: 8 MFMAs (A rows = edges, verified mapping) ----
    f32x4 c0 = {0.f, 0.f, 0.f, 0.f}, c1 = {0.f, 0.f, 0.f, 0.f};
    {
        f16x8 af;
        af = lrelu8(a0, v0);
        c0 = __builtin_amdgcn_mfma_f32_16x16x32_f16(af, bf0[0], c0, 0, 0, 0);
        c1 = __builtin_amdgcn_mfma_f32_16x16x32_f16(af, bf1[0], c1, 0, 0, 0);
        af = lrelu8(a1, v1);
        c0 = __builtin_amdgcn_mfma_f32_16x16x32_f16(af, bf0[1], c0, 0, 0, 0);
        c1 = __builtin_amdgcn_mfma_f32_16x16x32_f16(af, bf1[1], c1, 0, 0, 0);
        af = lrelu8(a2, v2);
        c0 = __builtin_amdgcn_mfma_f32_16x16x32_f16(af, bf0[2], c0, 0, 0, 0);
        c1 = __builtin_amdgcn_mfma_f32_16x16x32_f16(af, bf1[2], c1, 0, 0, 0);
        af = lrelu8(a3, v3);
        c0 = __builtin_amdgcn_mfma_f32_16x16x32_f16(af, bf0[3], c0, 0, 0, 0);
        c1 = __builtin_amdgcn_mfma_f32_16x16x32_f16(af, bf1[3], c1, 0, 0, 0);
    }

    // ---- h2 = lrelu(D + b2) -> wave-private LDS slab [16][40] f16 ----
#pragma unroll
    for (int r = 0; r < 4; ++r) {
        const int e = 4 * cg + r;
        Hw[e * 40 + er]      = (_Float16)lreluf(c0[r] + b2v0);
        Hw[e * 40 + 16 + er] = (_Float16)lreluf(c1[r] + b2v1);
    }

    // ---- layer 3 MFMA (swapped operands) + layer-4 shfl reduce ----
    // B-frag: h2^T — lane reads h2[edge=er][8*cg..+7] as one b128
    f16x8 hv = *(const f16x8*)&Hw[er * 40 + 8 * cg];
    f32x4 d3 = __builtin_amdgcn_mfma_f32_16x16x32_f16(
        w3f, hv, (f32x4){0.f, 0.f, 0.f, 0.f}, 0, 0, 0);

    float v = lreluf(d3[0] + b3q.x) * w4q.x;
    v      += lreluf(d3[1] + b3q.y) * w4q.y;
    v      += lreluf(d3[2] + b3q.z) * w4q.z;
    v      += lreluf(d3[3] + b3q.w) * w4q.w;
    v += __shfl_xor(v, 16, 64);
    v += __shfl_xor(v, 32, 64);

    if (cg == 0) {
        const int eo = base + er;
        if (eo < E) out[eo] = v + b4v;
    }
}

// ---------------------------------------------------------------------------
extern "C" void kernel_launch(void* const* d_in, const int* in_sizes, int n_in,
                              void* d_out, int out_size, void* d_ws, size_t ws_size,
                              hipStream_t stream)
{
    const float* x_drug = (const float*)d_in[0];
    const float* x_dis  = (const float*)d_in[1];
    const void*  eidx   = d_in[2];
    const float* W1 = (const float*)d_in[3];
    const float* b1 = (const float*)d_in[4];
    const float* W2 = (const float*)d_in[5];
    const float* b2 = (const float*)d_in[6];
    const float* W3 = (const float*)d_in[7];
    const float* b3 = (const float*)d_in[8];
    const float* W4 = (const float*)d_in[9];
    const float* b4 = (const float*)d_in[10];

    const int nd = in_sizes[0] / 100;
    const int ni = in_sizes[1] / 100;
    const int E  = in_sizes[2] / 2;

    char* ws = (char*)d_ws;
    _Float16* Pd  = (_Float16*)ws;                   size_t off = (size_t)nd * 128 * 2;
    _Float16* Pi  = (_Float16*)(ws + off);           off += (size_t)ni * 128 * 2;
    _Float16* W2f = (_Float16*)(ws + off);           off += 4096 * 2;
    _Float16* W3f = (_Float16*)(ws + off);           off += 512 * 2;
    int* flag = (int*)(ws + off);

    const int nblk_d = (nd + 15) / 16;
    const int nblk_i = (ni + 15) / 16;

    node_proj2<<<nblk_d + nblk_i + 2, 256, 0, stream>>>(
        x_drug, x_dis, W1, b1, Pd, Pi, nd, ni, nblk_d, nblk_i,
        W2, W3, W2f, W3f,
        (const unsigned*)eidx, 2LL * E, flag);

    edge_mlp<<<(E + 127) / 128, 512, 0, stream>>>(eidx, Pd, Pi,
                                                  W2f, b2, W3f, b3, W4, b4,
                                                  flag, (float*)d_out, E);
}

// Round 11
// 160.241 us; speedup vs baseline: 1.0866x; 1.0866x over previous
//
#include <hip/hip_runtime.h>
#include <cstdint>
#include <cstddef>

typedef _Float16 hf2   __attribute__((ext_vector_type(2)));
typedef _Float16 f16x8 __attribute__((ext_vector_type(8)));
typedef float    f32x4 __attribute__((ext_vector_type(4)));
typedef unsigned int u32x4 __attribute__((ext_vector_type(4)));

__device__ __forceinline__ f16x8 b2h8(u32x4 q) { union { u32x4 q; f16x8 h; } c; c.q = q; return c.h; }
__device__ __forceinline__ float lreluf(float x) { return fmaxf(x, 0.01f * x); }
__device__ __forceinline__ f16x8 lrelu8(u32x4 a, u32x4 b) {
    f16x8 s = b2h8(a) + b2h8(b);
    f16x8 m = s * (_Float16)0.01f;
    return __builtin_elementwise_max(s, m);
}

// Pinned 16B global load (r9 lesson: C++ loads get sunk to uses; asm doesn't).
#define GLOAD(dst, ptr, off) \
    asm volatile("global_load_dwordx4 %0, %1, off offset:" #off \
                 : "=v"(dst) : "v"(ptr) : "memory")
#define VMCNT(n) do { \
    asm volatile("s_waitcnt vmcnt(" #n ")" ::: "memory"); \
    __builtin_amdgcn_sched_barrier(0); } while (0)

// ---------------------------------------------------------------------------
// node projection + (extra blocks) weight packing + index-format detect.
__global__ __launch_bounds__(256) void node_proj2(
    const float* __restrict__ xd, const float* __restrict__ xi,
    const float* __restrict__ W1, const float* __restrict__ b1,
    _Float16* __restrict__ Pd, _Float16* __restrict__ Pi,
    int nd, int ni, int nblk_d, int nblk_i,
    const float* __restrict__ W2, const float* __restrict__ W3,
    _Float16* __restrict__ W2f, _Float16* __restrict__ W3f,
    const unsigned* __restrict__ ew, long long nwords, int* __restrict__ flag)
{
    const int t = threadIdx.x;
    const int nproj = nblk_d + nblk_i;

    if ((int)blockIdx.x >= nproj) {
        if ((int)blockIdx.x == nproj) {
            // W2 as MFMA B-fragments: B[k=kt*32+8*(l>>4)+i][col=nt*16+(l&15)]
            for (int idx = t; idx < 4096; idx += 256) {
                int i  = idx & 7;
                int l  = (idx >> 3) & 63;
                int kt = (idx >> 9) & 3;
                int nt = (idx >> 11) & 1;
                int k = kt * 32 + 8 * (l >> 4) + i;
                int j = nt * 16 + (l & 15);
                W2f[idx] = (_Float16)W2[k * 32 + j];
            }
            // W3^T as MFMA A-fragment: lane l, elem i -> W3[k=8*(l>>4)+i][row=l&15]
            for (int idx = t; idx < 512; idx += 256) {
                int i = idx & 7, l = idx >> 3;
                W3f[idx] = (_Float16)W3[(8 * (l >> 4) + i) * 16 + (l & 15)];
            }
        } else if (t < 64) {
            const long long pairs = nwords / 2;
            const long long step  = pairs / 64;
            unsigned v = 0;
            for (int s = 0; s < 4; ++s) {
                long long p = (long long)t * step + (long long)s * (step / 4 + 1);
                if (p < pairs) v |= ew[2 * p + 1];
            }
            unsigned long long ball = __ballot(v != 0);
            if (t == 0) *flag = (ball == 0ULL) ? 1 : 0;
        }
        return;
    }

    __shared__ float xs[1600];
    const int c  = t & 127;
    const int ty = t >> 7;
    const bool dis = (int)blockIdx.x >= nblk_d;
    const int b = dis ? (blockIdx.x - nblk_d) : blockIdx.x;
    const int n = dis ? ni : nd;
    const float* x = dis ? xi : xd;
    const float* W = dis ? (W1 + 100 * 128) : W1;
    _Float16* P = dis ? Pi : Pd;
    const float bv = dis ? b1[c] : 0.f;
    const int r0 = b * 16;

    const long long gbase = (long long)r0 * 100;
    const long long lim   = (long long)n * 100;
    for (int idx = t; idx < 1600; idx += 256) {
        long long g = gbase + idx;
        xs[idx] = (g < lim) ? x[g] : 0.f;
    }
    __syncthreads();

    float acc[8];
#pragma unroll
    for (int i = 0; i < 8; ++i) acc[i] = bv;

    const float4* xs4 = (const float4*)xs;
#pragma unroll 5
    for (int kk = 0; kk < 25; ++kk) {
        float w0 = W[(4 * kk + 0) * 128 + c];
        float w1 = W[(4 * kk + 1) * 128 + c];
        float w2 = W[(4 * kk + 2) * 128 + c];
        float w3 = W[(4 * kk + 3) * 128 + c];
#pragma unroll
        for (int i = 0; i < 8; ++i) {
            float4 xv = xs4[(ty * 8 + i) * 25 + kk];
            acc[i] = fmaf(xv.x, w0, acc[i]);
            acc[i] = fmaf(xv.y, w1, acc[i]);
            acc[i] = fmaf(xv.z, w2, acc[i]);
            acc[i] = fmaf(xv.w, w3, acc[i]);
        }
    }
#pragma unroll
    for (int i = 0; i < 8; ++i) {
        int r = r0 + ty * 8 + i;
        if (r < n) P[(size_t)r * 128 + c] = (_Float16)acc[i];
    }
}

// ---------------------------------------------------------------------------
// Edge MLP: 256 threads = 4 waves; wave owns 64 edges = 4 tiles of 16.
// Pinned-asm gather pipeline, 2 tiles (16 loads) in flight, counted vmcnt.
// Per-tile: 8 gathers (16 full 64B lines), lrelu in regs, 8+1 MFMAs.
__global__ __launch_bounds__(256, 3) void edge_mlp(
    const void* __restrict__ eidx_raw,
    const _Float16* __restrict__ Pd, const _Float16* __restrict__ Pi,
    const _Float16* __restrict__ W2f, const float* __restrict__ b2,
    const float* __restrict__ b3,
    const float* __restrict__ W4, const float* __restrict__ b4,
    const int* __restrict__ flag64,
    float* __restrict__ out, int E)
{
    __shared__ __align__(16) u32x4    Ws[576];        // W2 frags(512) + W3^T frag(64), 9 KB
    __shared__ __align__(16) _Float16 H2s[4][64 * 40]; // 20 KB, wave-private slabs

    const int t  = threadIdx.x;
    const int l  = t & 63;
    const int w  = t >> 6;
    const int er = l & 15;
    const int cg = l >> 4;
    const int base = blockIdx.x * 256 + w * 64;
    _Float16* Hw = H2s[w];

    const int f = *flag64;   // issued at top; latency hidden by stage+barrier

    // ---- stage weight fragments to LDS (W2f,W3f contiguous in ws) ----
    {
        const u32x4* src = (const u32x4*)W2f;
        for (int idx = t; idx < 576; idx += 256) Ws[idx] = src[idx];
    }
    __syncthreads();

    // ---- per-lane edge indices, branch-free address select ----
    const int e_c = min(base + l, E - 1);
    const char* pb = (const char*)eidx_raw;
    const int i0 = *(const int*)(pb + (f ? 8 * (size_t)e_c : 4 * (size_t)e_c));
    const int i1 = *(const int*)(pb + (f ? 8 * ((size_t)E + e_c) : 4 * ((size_t)E + e_c)));

    int j0[4], j1[4];
#pragma unroll
    for (int q = 0; q < 4; ++q) {
        j0[q] = __shfl(i0, q * 16 + er, 64);
        j1[q] = __shfl(i1, q * 16 + er, 64);
    }
    const char* pD0 = (const char*)(Pd + (size_t)j0[0] * 128) + cg * 16;
    const char* pI0 = (const char*)(Pi + (size_t)j1[0] * 128) + cg * 16;
    const char* pD1 = (const char*)(Pd + (size_t)j0[1] * 128) + cg * 16;
    const char* pI1 = (const char*)(Pi + (size_t)j1[1] * 128) + cg * 16;
    const char* pD2 = (const char*)(Pd + (size_t)j0[2] * 128) + cg * 16;
    const char* pI2 = (const char*)(Pi + (size_t)j1[2] * 128) + cg * 16;
    const char* pD3 = (const char*)(Pd + (size_t)j0[3] * 128) + cg * 16;
    const char* pI3 = (const char*)(Pi + (size_t)j1[3] * 128) + cg * 16;

    const float b2v0 = b2[er], b2v1 = b2[16 + er];

#define ISSUE(A, V, pD, pI) do { \
    GLOAD(A##0, pD, 0); GLOAD(A##1, pD, 64); GLOAD(A##2, pD, 128); GLOAD(A##3, pD, 192); \
    GLOAD(V##0, pI, 0); GLOAD(V##1, pI, 64); GLOAD(V##2, pI, 128); GLOAD(V##3, pI, 192); } while (0)

#define CONSUME(q, A, V) do { \
    f32x4 c0 = {0.f,0.f,0.f,0.f}, c1 = {0.f,0.f,0.f,0.f}; \
    f16x8 af; \
    af = lrelu8(A##0, V##0); \
    c0 = __builtin_amdgcn_mfma_f32_16x16x32_f16(af, b2h8(Ws[0 * 64 + l]), c0, 0, 0, 0); \
    c1 = __builtin_amdgcn_mfma_f32_16x16x32_f16(af, b2h8(Ws[256 + 0 * 64 + l]), c1, 0, 0, 0); \
    af = lrelu8(A##1, V##1); \
    c0 = __builtin_amdgcn_mfma_f32_16x16x32_f16(af, b2h8(Ws[1 * 64 + l]), c0, 0, 0, 0); \
    c1 = __builtin_amdgcn_mfma_f32_16x16x32_f16(af, b2h8(Ws[256 + 1 * 64 + l]), c1, 0, 0, 0); \
    af = lrelu8(A##2, V##2); \
    c0 = __builtin_amdgcn_mfma_f32_16x16x32_f16(af, b2h8(Ws[2 * 64 + l]), c0, 0, 0, 0); \
    c1 = __builtin_amdgcn_mfma_f32_16x16x32_f16(af, b2h8(Ws[256 + 2 * 64 + l]), c1, 0, 0, 0); \
    af = lrelu8(A##3, V##3); \
    c0 = __builtin_amdgcn_mfma_f32_16x16x32_f16(af, b2h8(Ws[3 * 64 + l]), c0, 0, 0, 0); \
    c1 = __builtin_amdgcn_mfma_f32_16x16x32_f16(af, b2h8(Ws[256 + 3 * 64 + l]), c1, 0, 0, 0); \
    _Pragma("unroll") \
    for (int r = 0; r < 4; ++r) { \
        const int e = (q) * 16 + 4 * cg + r; \
        Hw[e * 40 + er]      = (_Float16)lreluf(c0[r] + b2v0); \
        Hw[e * 40 + 16 + er] = (_Float16)lreluf(c1[r] + b2v1); \
    } } while (0)

    u32x4 A00, A01, A02, A03, V00, V01, V02, V03;   // ping
    u32x4 A10, A11, A12, A13, V10, V11, V12, V13;   // pong

    ISSUE(A0, V0, pD0, pI0);
    ISSUE(A1, V1, pD1, pI1);
    VMCNT(8);                 // tile0 ready, tile1 in flight
    CONSUME(0, A0, V0);
    ISSUE(A0, V0, pD2, pI2);  // tile2 -> ping (WAR after consume 0)
    VMCNT(8);                 // tile1 ready, tile2 in flight
    CONSUME(1, A1, V1);
    ISSUE(A1, V1, pD3, pI3);  // tile3 -> pong
    VMCNT(8);                 // tile2 ready
    CONSUME(2, A0, V0);
    VMCNT(0);                 // tile3 ready
    CONSUME(3, A1, V1);

#undef ISSUE
#undef CONSUME

    // ---- layer 3 MFMA (swapped operands) + layer-4 shfl reduce ----
    const f16x8 w3f = b2h8(Ws[512 + l]);
    const float4 b3q = ((const float4*)b3)[cg];
    const float4 w4q = ((const float4*)W4)[cg];
    const float  b4v = b4[0];

#pragma unroll
    for (int q = 0; q < 4; ++q) {
        const int e2 = q * 16 + er;
        f16x8 hv = *(const f16x8*)&Hw[e2 * 40 + 8 * cg];   // h2^T B-frag, one b128
        f32x4 d3 = __builtin_amdgcn_mfma_f32_16x16x32_f16(
            w3f, hv, (f32x4){0.f, 0.f, 0.f, 0.f}, 0, 0, 0);

        float v = lreluf(d3[0] + b3q.x) * w4q.x;
        v      += lreluf(d3[1] + b3q.y) * w4q.y;
        v      += lreluf(d3[2] + b3q.z) * w4q.z;
        v      += lreluf(d3[3] + b3q.w) * w4q.w;
        v += __shfl_xor(v, 16, 64);
        v += __shfl_xor(v, 32, 64);

        if (cg == 0) {
            const int eo = base + q * 16 + er;
            if (eo < E) out[eo] = v + b4v;
        }
    }
}

// ---------------------------------------------------------------------------
extern "C" void kernel_launch(void* const* d_in, const int* in_sizes, int n_in,
                              void* d_out, int out_size, void* d_ws, size_t ws_size,
                              hipStream_t stream)
{
    const float* x_drug = (const float*)d_in[0];
    const float* x_dis  = (const float*)d_in[1];
    const void*  eidx   = d_in[2];
    const float* W1 = (const float*)d_in[3];
    const float* b1 = (const float*)d_in[4];
    const float* W2 = (const float*)d_in[5];
    const float* b2 = (const float*)d_in[6];
    const float* W3 = (const float*)d_in[7];
    const float* b3 = (const float*)d_in[8];
    const float* W4 = (const float*)d_in[9];
    const float* b4 = (const float*)d_in[10];

    const int nd = in_sizes[0] / 100;
    const int ni = in_sizes[1] / 100;
    const int E  = in_sizes[2] / 2;

    char* ws = (char*)d_ws;
    _Float16* Pd  = (_Float16*)ws;                   size_t off = (size_t)nd * 128 * 2;
    _Float16* Pi  = (_Float16*)(ws + off);           off += (size_t)ni * 128 * 2;
    _Float16* W2f = (_Float16*)(ws + off);           off += 4096 * 2;
    _Float16* W3f = (_Float16*)(ws + off);           off += 512 * 2;
    int* flag = (int*)(ws + off);

    const int nblk_d = (nd + 15) / 16;
    const int nblk_i = (ni + 15) / 16;

    node_proj2<<<nblk_d + nblk_i + 2, 256, 0, stream>>>(
        x_drug, x_dis, W1, b1, Pd, Pi, nd, ni, nblk_d, nblk_i,
        W2, W3, W2f, W3f,
        (const unsigned*)eidx, 2LL * E, flag);

    edge_mlp<<<(E + 255) / 256, 256, 0, stream>>>(eidx, Pd, Pi,
                                                  W2f, b2, b3, W4, b4,
                                                  flag, (float*)d_out, E);
}